// Round 1
// baseline (5450.262 us; speedup 1.0000x reference)
//
#include <hip/hip_runtime.h>

#define N_SUP 8192
#define N_QPT 2048

// ---------------------------------------------------------------------------
// Exactness helpers: the reference index selection (FPS argmax, ball-query
// membership) must match numpy's plain fp32 arithmetic bit-for-bit, so fma
// contraction is disabled for these expressions.
// ---------------------------------------------------------------------------
__device__ __forceinline__ float sumsq3(float x, float y, float z) {
#pragma clang fp contract(off)
  return x * x + y * y + z * z;  // ((x*x + y*y) + z*z)
}

__device__ __forceinline__ float sqdist3(float ax, float ay, float az,
                                         float bx, float by, float bz) {
#pragma clang fp contract(off)
  float dx = ax - bx, dy = ay - by, dz = az - bz;
  return dx * dx + dy * dy + dz * dz;
}

__device__ __forceinline__ float dot3(float ax, float ay, float az,
                                      float bx, float by, float bz) {
#pragma clang fp contract(off)
  return ax * bx + ay * by + az * bz;
}

__device__ __forceinline__ float d2_expand(float A, float Bn, float d) {
#pragma clang fp contract(off)
  return (A + Bn) - 2.0f * d;  // matches (|q|^2 + |s|^2) - 2*dot
}

// ---------------------------------------------------------------------------
// prep: xyz (B,N,3) -> SoA xs/ys/zs + per-point squared norms
// ---------------------------------------------------------------------------
__global__ __launch_bounds__(256) void prep_xyz_kernel(
    const float* __restrict__ xyz, float* __restrict__ xs,
    float* __restrict__ ys, float* __restrict__ zs, float* __restrict__ bsq) {
  int p = blockIdx.x * 256 + threadIdx.x;  // 0..B*N-1
  float x = xyz[p * 3 + 0];
  float y = xyz[p * 3 + 1];
  float z = xyz[p * 3 + 2];
  xs[p] = x; ys[p] = y; zs[p] = z;
  bsq[p] = sumsq3(x, y, z);
}

// ---------------------------------------------------------------------------
// transpose features (B,C=64,N) -> (B,N,64) for coalesced gathers
// ---------------------------------------------------------------------------
__global__ __launch_bounds__(256) void transpose_feats_kernel(
    const float* __restrict__ feats, float* __restrict__ fT) {
  __shared__ float tile[64][65];
  int b = blockIdx.x >> 7;           // 128 n-tiles per batch
  int nb = (blockIdx.x & 127) << 6;
  int t = threadIdx.x;
#pragma unroll
  for (int i = 0; i < 16; ++i) {
    int e = i * 256 + t;
    int c = e >> 6, n = e & 63;     // consecutive lanes -> consecutive n
    tile[n][c] = feats[(b * 64 + c) * N_SUP + nb + n];
  }
  __syncthreads();
#pragma unroll
  for (int i = 0; i < 16; ++i) {
    int e = i * 256 + t;
    int n = e >> 6, c = e & 63;     // consecutive lanes -> consecutive c
    fT[(b * N_SUP + nb + n) * 64 + c] = tile[n][c];
  }
}

// ---------------------------------------------------------------------------
// FPS: one block per batch (sequential 2047-step chain). 512 threads hold all
// 8192 points + running min-dists in registers; per iteration: min-update,
// block argmax (first-index tie-break), winner coords carried through the
// reduction so only ONE barrier per iteration (double-buffered partials).
// ---------------------------------------------------------------------------
__global__ __launch_bounds__(512, 1) void fps_kernel(
    const float* __restrict__ xs, const float* __restrict__ ys,
    const float* __restrict__ zs, float* __restrict__ qxyz) {
  const int b = blockIdx.x;
  const int t = threadIdx.x;
  const float* bx = xs + b * N_SUP;
  const float* by = ys + b * N_SUP;
  const float* bz = zs + b * N_SUP;
  float px[16], py[16], pz[16], dm[16];
#pragma unroll
  for (int j = 0; j < 16; ++j) {
    int n = t + j * 512;
    px[j] = bx[n]; py[j] = by[n]; pz[j] = bz[n];
    dm[j] = 1e10f;
  }
  __shared__ float s_v[2][8], s_x[2][8], s_y[2][8], s_z[2][8];
  __shared__ int s_i[2][8];
  float lx = bx[0], ly = by[0], lz = bz[0];
  float* q = qxyz + b * N_QPT * 3;
  if (t == 0) { q[0] = lx; q[1] = ly; q[2] = lz; }
  const int wv = t >> 6, ln = t & 63;
  for (int it = 1; it < N_QPT; ++it) {
    float bd = -1.0f; int bi = 0;
    float cx = 0.f, cy = 0.f, cz = 0.f;
#pragma unroll
    for (int j = 0; j < 16; ++j) {
      float d = sqdist3(px[j], py[j], pz[j], lx, ly, lz);
      float nd = fminf(dm[j], d);
      dm[j] = nd;
      bool tk = nd > bd;  // j ascending == index ascending: strict > keeps first
      bd = tk ? nd : bd;
      bi = tk ? (t + j * 512) : bi;
      cx = tk ? px[j] : cx; cy = tk ? py[j] : cy; cz = tk ? pz[j] : cz;
    }
#pragma unroll
    for (int off = 32; off >= 1; off >>= 1) {
      float ov = __shfl_down(bd, off);
      int oi = __shfl_down(bi, off);
      float ox = __shfl_down(cx, off);
      float oy = __shfl_down(cy, off);
      float oz = __shfl_down(cz, off);
      bool tk = (ov > bd) || (ov == bd && oi < bi);
      bd = tk ? ov : bd; bi = tk ? oi : bi;
      cx = tk ? ox : cx; cy = tk ? oy : cy; cz = tk ? oz : cz;
    }
    const int par = it & 1;
    if (ln == 0) {
      s_v[par][wv] = bd; s_i[par][wv] = bi;
      s_x[par][wv] = cx; s_y[par][wv] = cy; s_z[par][wv] = cz;
    }
    __syncthreads();
    float rv = s_v[par][0]; int ri = s_i[par][0];
    float rx = s_x[par][0], ry = s_y[par][0], rz = s_z[par][0];
#pragma unroll
    for (int k = 1; k < 8; ++k) {
      float v2 = s_v[par][k]; int i2 = s_i[par][k];
      bool tk = (v2 > rv) || (v2 == rv && i2 < ri);
      rv = tk ? v2 : rv; ri = tk ? i2 : ri;
      rx = tk ? s_x[par][k] : rx;
      ry = tk ? s_y[par][k] : ry;
      rz = tk ? s_z[par][k] : rz;
    }
    lx = rx; ly = ry; lz = rz;
    if (t == 0) { q[it * 3 + 0] = rx; q[it * 3 + 1] = ry; q[it * 3 + 2] = rz; }
  }
}

// ---------------------------------------------------------------------------
// Ball query: one wave per query, both radii in one scan. First-K-by-index
// via ballot + prefix popcount; early exit when both lists are full; pad with
// the first in-ball index (always exists: the query point itself, d2==0).
// ---------------------------------------------------------------------------
__global__ __launch_bounds__(256) void ballquery_kernel(
    const float* __restrict__ qxyz, const float* __restrict__ xs,
    const float* __restrict__ ys, const float* __restrict__ zs,
    const float* __restrict__ bsq, int* __restrict__ idx0,
    int* __restrict__ idx1) {
  const int lane = threadIdx.x & 63;
  const int qg = (blockIdx.x * 256 + threadIdx.x) >> 6;  // 0..16383
  const int b = qg >> 11;
  const float qx = qxyz[qg * 3 + 0];
  const float qy = qxyz[qg * 3 + 1];
  const float qz = qxyz[qg * 3 + 2];
  const float A = sumsq3(qx, qy, qz);
  const float* sx = xs + b * N_SUP;
  const float* sy = ys + b * N_SUP;
  const float* sz = zs + b * N_SUP;
  const float* sq = bsq + b * N_SUP;
  int* o0 = idx0 + qg * 16;
  int* o1 = idx1 + qg * 32;
  int cnt0 = 0, cnt1 = 0, first0 = 0, first1 = 0;
  const unsigned long long ltmask = (1ull << lane) - 1ull;
  for (int base = 0; base < N_SUP; base += 64) {
    int n = base + lane;
    float d = dot3(qx, qy, qz, sx[n], sy[n], sz[n]);
    float d2 = d2_expand(A, sq[n], d);
    bool in1 = d2 <= 0.04f;  // == f32(0.2*0.2 in double)
    bool in0 = d2 <= 0.01f;  // == f32(0.1*0.1 in double)
    unsigned long long m1 = __ballot(in1);
    unsigned long long m0 = __ballot(in0);
    if (in1) {
      int pos = cnt1 + __popcll(m1 & ltmask);
      if (pos < 32) o1[pos] = n;
    }
    if (in0) {
      int pos = cnt0 + __popcll(m0 & ltmask);
      if (pos < 16) o0[pos] = n;
    }
    if (cnt1 == 0 && m1 != 0ull) first1 = base + __ffsll(m1) - 1;
    if (cnt0 == 0 && m0 != 0ull) first0 = base + __ffsll(m0) - 1;
    cnt1 += __popcll(m1);
    cnt0 += __popcll(m0);
    if (cnt0 >= 16 && cnt1 >= 32) break;
  }
  for (int p = cnt0 + lane; p < 16; p += 64) o0[p] = first0;
  for (int p = cnt1 + lane; p < 32; p += 64) o1[p] = first1;
}

// ---------------------------------------------------------------------------
// Grouped MLP. Block = 256 threads = 4 waves, 64 rows (= Q queries x K
// neighbors), lane == row. Activations in LDS with odd strides (bank-clean),
// weights are wave-uniform -> scalar loads feeding v_fmac: VALU-bound.
// ---------------------------------------------------------------------------
template <int CIN, int SIN, int D, int SOUT>
__device__ __forceinline__ void dense_layer(const float* __restrict__ hin,
                                            float* __restrict__ hout,
                                            const float* __restrict__ W,
                                            const float* __restrict__ Bv,
                                            int w, int lane) {
  constexpr int CH = D / 16;
#pragma unroll
  for (int pass = 0; pass * 4 < CH; ++pass) {
    const int chunk = pass * 4 + w;
    if (chunk < CH) {  // wave-uniform branch
      const int co = chunk * 16;
      float acc[16];
#pragma unroll
      for (int j = 0; j < 16; ++j) acc[j] = Bv[co + j];
      const float* hr = hin + lane * SIN;
      const float* wp = W + co;
#pragma unroll 4
      for (int c = 0; c < CIN; ++c) {
        float a = hr[c];
#pragma unroll
        for (int j = 0; j < 16; ++j) acc[j] = fmaf(a, wp[c * D + j], acc[j]);
      }
      float* ho = hout + lane * SOUT + co;
#pragma unroll
      for (int j = 0; j < 16; ++j) ho[j] = fmaxf(acc[j], 0.0f);
    }
  }
}

template <int K, int Q, int C2, int S2, int CHOFF>
__global__ __launch_bounds__(256, 4) void mlp_kernel(
    const int* __restrict__ idxl, const float* __restrict__ qxyz,
    const float* __restrict__ xs, const float* __restrict__ ys,
    const float* __restrict__ zs, const float* __restrict__ fT,
    const float* __restrict__ W1, const float* __restrict__ B1,
    const float* __restrict__ W2, const float* __restrict__ B2,
    const float* __restrict__ W3, const float* __restrict__ B3,
    float* __restrict__ outf) {
  constexpr int S0 = 67, S1 = 65;
  constexpr int H0 = 64 * S0, H1 = 64 * S1, H2 = 64 * S2;
  constexpr int SM = H1 + (H2 > H0 ? H2 : H0);
  __shared__ float smem[SM];
  float* h1 = smem;       // layer1 output
  float* h0 = smem + H1;  // gathered input; dead after layer1
  float* h2 = smem + H1;  // layer2 output overlays h0
  const int t = threadIdx.x;
  const int w = __builtin_amdgcn_readfirstlane(t >> 6);
  const int lane = t & 63;
  // ---- gather h0: [rel_x, rel_y, rel_z, feat0..63] per row ----
  for (int e = t; e < H0; e += 256) {
    int r = e / S0, c = e - r * S0;
    int qi = r / K, k = r - qi * K;
    int qg = blockIdx.x * Q + qi;
    int b = qg >> 11;
    int n = idxl[qg * K + k];
    float v;
    if (c < 3) {
      const float* sp = (c == 0) ? xs : (c == 1) ? ys : zs;
      v = sp[b * N_SUP + n] - qxyz[qg * 3 + c];
    } else {
      v = fT[(b * N_SUP + n) * 64 + (c - 3)];
    }
    h0[e] = v;
  }
  __syncthreads();
  dense_layer<67, S0, 64, S1>(h0, h1, W1, B1, w, lane);
  __syncthreads();
  dense_layer<64, S1, C2, S2>(h1, h2, W2, B2, w, lane);
  __syncthreads();
  // ---- layer3 (C2 -> 128) + relu + maxpool over K + channel-major write ----
#pragma unroll
  for (int pass = 0; pass < 2; ++pass) {
    const int co = (pass * 4 + w) * 16;
    float acc[16];
#pragma unroll
    for (int j = 0; j < 16; ++j) acc[j] = B3[co + j];
    const float* hr = h2 + lane * S2;
#pragma unroll 4
    for (int c = 0; c < C2; ++c) {
      float a = hr[c];
#pragma unroll
      for (int j = 0; j < 16; ++j) acc[j] = fmaf(a, W3[c * 128 + co + j], acc[j]);
    }
#pragma unroll
    for (int j = 0; j < 16; ++j) acc[j] = fmaxf(acc[j], 0.0f);
#pragma unroll
    for (int off = K / 2; off >= 1; off >>= 1) {
#pragma unroll
      for (int j = 0; j < 16; ++j)
        acc[j] = fmaxf(acc[j], __shfl_xor(acc[j], off));
    }
    if ((lane & (K - 1)) == 0) {
      int qg = blockIdx.x * Q + (lane / K);
      int b = qg >> 11, s = qg & 2047;
      float* dst = outf + ((b * 256 + CHOFF + co) * 2048 + s);
#pragma unroll
      for (int j = 0; j < 16; ++j) dst[j * 2048] = acc[j];
    }
  }
}

// ---------------------------------------------------------------------------
// ws layout (floats): xs[65536] ys[65536] zs[65536] bsq[65536]
// featsT[8*8192*64] then idx0 (8*2048*16 int), idx1 (8*2048*32 int) ~20 MB
// ---------------------------------------------------------------------------
extern "C" void kernel_launch(void* const* d_in, const int* in_sizes, int n_in,
                              void* d_out, int out_size, void* d_ws,
                              size_t ws_size, hipStream_t stream) {
  const float* xyz = (const float*)d_in[0];
  const float* feats = (const float*)d_in[1];
  const float* wt[12];
  for (int i = 0; i < 12; ++i) wt[i] = (const float*)d_in[2 + i];

  float* ws = (float*)d_ws;
  float* xs = ws;
  float* ys = ws + 65536;
  float* zs = ws + 131072;
  float* bsq = ws + 196608;
  float* fT = ws + 262144;                 // 4194304 floats
  int* idx0 = (int*)(ws + 4456448);        // 262144 ints
  int* idx1 = idx0 + 262144;               // 524288 ints

  float* qxyz = (float*)d_out;             // (8,2048,3)
  float* outf = qxyz + 8 * 2048 * 3;       // (8,256,2048)

  prep_xyz_kernel<<<dim3(256), dim3(256), 0, stream>>>(xyz, xs, ys, zs, bsq);
  transpose_feats_kernel<<<dim3(1024), dim3(256), 0, stream>>>(feats, fT);
  fps_kernel<<<dim3(8), dim3(512), 0, stream>>>(xs, ys, zs, qxyz);
  ballquery_kernel<<<dim3(4096), dim3(256), 0, stream>>>(qxyz, xs, ys, zs, bsq,
                                                         idx0, idx1);
  mlp_kernel<16, 4, 64, 65, 0><<<dim3(4096), dim3(256), 0, stream>>>(
      idx0, qxyz, xs, ys, zs, fT, wt[0], wt[1], wt[2], wt[3], wt[4], wt[5],
      outf);
  mlp_kernel<32, 2, 96, 97, 128><<<dim3(8192), dim3(256), 0, stream>>>(
      idx1, qxyz, xs, ys, zs, fT, wt[6], wt[7], wt[8], wt[9], wt[10], wt[11],
      outf);
}

// Round 2
// 3143.575 us; speedup vs baseline: 1.7338x; 1.7338x over previous
//
#include <hip/hip_runtime.h>

#define N_SUP 8192
#define N_QPT 2048

// ---------------------------------------------------------------------------
// Exactness helpers: the reference index selection (FPS argmax, ball-query
// membership) must match numpy's plain fp32 arithmetic bit-for-bit, so fma
// contraction is disabled for these expressions.
// ---------------------------------------------------------------------------
__device__ __forceinline__ float sumsq3(float x, float y, float z) {
#pragma clang fp contract(off)
  return x * x + y * y + z * z;  // ((x*x + y*y) + z*z)
}

__device__ __forceinline__ float sqdist3(float ax, float ay, float az,
                                         float bx, float by, float bz) {
#pragma clang fp contract(off)
  float dx = ax - bx, dy = ay - by, dz = az - bz;
  return dx * dx + dy * dy + dz * dz;
}

__device__ __forceinline__ float dot3(float ax, float ay, float az,
                                      float bx, float by, float bz) {
#pragma clang fp contract(off)
  return ax * bx + ay * by + az * bz;
}

__device__ __forceinline__ float d2_expand(float A, float Bn, float d) {
#pragma clang fp contract(off)
  return (A + Bn) - 2.0f * d;  // matches (|q|^2 + |s|^2) - 2*dot
}

// ---------------------------------------------------------------------------
// prep: xyz (B,N,3) -> SoA xs/ys/zs + per-point squared norms
// ---------------------------------------------------------------------------
__global__ __launch_bounds__(256) void prep_xyz_kernel(
    const float* __restrict__ xyz, float* __restrict__ xs,
    float* __restrict__ ys, float* __restrict__ zs, float* __restrict__ bsq) {
  int p = blockIdx.x * 256 + threadIdx.x;  // 0..B*N-1
  float x = xyz[p * 3 + 0];
  float y = xyz[p * 3 + 1];
  float z = xyz[p * 3 + 2];
  xs[p] = x; ys[p] = y; zs[p] = z;
  bsq[p] = sumsq3(x, y, z);
}

// ---------------------------------------------------------------------------
// transpose features (B,C=64,N) -> (B,N,64) for coalesced gathers
// ---------------------------------------------------------------------------
__global__ __launch_bounds__(256) void transpose_feats_kernel(
    const float* __restrict__ feats, float* __restrict__ fT) {
  __shared__ float tile[64][65];
  int b = blockIdx.x >> 7;           // 128 n-tiles per batch
  int nb = (blockIdx.x & 127) << 6;
  int t = threadIdx.x;
#pragma unroll
  for (int i = 0; i < 16; ++i) {
    int e = i * 256 + t;
    int c = e >> 6, n = e & 63;     // consecutive lanes -> consecutive n
    tile[n][c] = feats[(b * 64 + c) * N_SUP + nb + n];
  }
  __syncthreads();
#pragma unroll
  for (int i = 0; i < 16; ++i) {
    int e = i * 256 + t;
    int n = e >> 6, c = e & 63;     // consecutive lanes -> consecutive c
    fT[(b * N_SUP + nb + n) * 64 + c] = tile[n][c];
  }
}

// ---------------------------------------------------------------------------
// FPS: one block per batch (sequential 2047-step chain). 512 threads hold all
// 8192 points + running min-dists in registers.
//
// Argmax per iteration via a single packed 64-bit key:
//   key = (float_bits(dist) << 32) | (8191 - idx)
// dist >= 0 so float bits are u32-monotone; inverted idx => unsigned max
// implements "largest dist, ties -> smallest index" exactly (numpy argmax).
// Winner coords are fetched from an LDS mirror of the point cloud instead of
// being carried through the tournament (1 value through shuffles, not 5).
// Double-buffered key slots => ONE barrier per iteration.
// ---------------------------------------------------------------------------
__global__ __launch_bounds__(512, 1) void fps_kernel(
    const float* __restrict__ xs, const float* __restrict__ ys,
    const float* __restrict__ zs, float* __restrict__ qxyz) {
  const int b = blockIdx.x;
  const int t = threadIdx.x;
  __shared__ float sx[N_SUP], sy[N_SUP], sz[N_SUP];  // 96 KB coord mirror
  __shared__ unsigned long long skey[2][8];
  const float* bx = xs + b * N_SUP;
  const float* by = ys + b * N_SUP;
  const float* bz = zs + b * N_SUP;
  float px[16], py[16], pz[16], dm[16];
#pragma unroll
  for (int j = 0; j < 16; ++j) {
    int n = t + j * 512;
    px[j] = bx[n]; py[j] = by[n]; pz[j] = bz[n];
    sx[n] = px[j]; sy[n] = py[j]; sz[n] = pz[j];
    dm[j] = 1e10f;
  }
  // LDS mirror writes are ordered before first use by iteration 1's barrier.
  float lx = bx[0], ly = by[0], lz = bz[0];
  float* q = qxyz + b * N_QPT * 3;
  if (t == 0) { q[0] = lx; q[1] = ly; q[2] = lz; }
  const int wv = t >> 6, ln = t & 63;
  for (int it = 1; it < N_QPT; ++it) {
    float bd = -1.0f; int bi = 0;
#pragma unroll
    for (int j = 0; j < 16; ++j) {
      float d = sqdist3(px[j], py[j], pz[j], lx, ly, lz);
      float nd = fminf(dm[j], d);
      dm[j] = nd;
      bool tk = nd > bd;  // j ascending == index ascending: strict > keeps first
      bd = tk ? nd : bd;
      bi = tk ? (t + j * 512) : bi;
    }
    unsigned long long key =
        (((unsigned long long)__float_as_uint(bd)) << 32) |
        (unsigned int)(N_SUP - 1 - bi);
#pragma unroll
    for (int off = 32; off >= 1; off >>= 1) {
      unsigned long long o = __shfl_down(key, off);
      key = (o > key) ? o : key;
    }
    const int par = it & 1;
    if (ln == 0) skey[par][wv] = key;
    __syncthreads();
    // 8-way broadcast merge (all threads redundantly; LDS broadcast is free)
    unsigned long long k0 = skey[par][0], k1 = skey[par][1];
    unsigned long long k2 = skey[par][2], k3 = skey[par][3];
    unsigned long long k4 = skey[par][4], k5 = skey[par][5];
    unsigned long long k6 = skey[par][6], k7 = skey[par][7];
    k0 = (k1 > k0) ? k1 : k0;
    k2 = (k3 > k2) ? k3 : k2;
    k4 = (k5 > k4) ? k5 : k4;
    k6 = (k7 > k6) ? k7 : k6;
    k0 = (k2 > k0) ? k2 : k0;
    k4 = (k6 > k4) ? k6 : k4;
    k0 = (k4 > k0) ? k4 : k0;
    int ri = N_SUP - 1 - (int)(unsigned int)(k0 & 0xFFFFFFFFull);
    lx = sx[ri]; ly = sy[ri]; lz = sz[ri];
    if (t == 0) { q[it * 3 + 0] = lx; q[it * 3 + 1] = ly; q[it * 3 + 2] = lz; }
  }
}

// ---------------------------------------------------------------------------
// Ball query: one wave per query, both radii in one scan. First-K-by-index
// via ballot + prefix popcount; early exit when both lists are full; pad with
// the first in-ball index (always exists: the query point itself, d2==0).
// ---------------------------------------------------------------------------
__global__ __launch_bounds__(256) void ballquery_kernel(
    const float* __restrict__ qxyz, const float* __restrict__ xs,
    const float* __restrict__ ys, const float* __restrict__ zs,
    const float* __restrict__ bsq, int* __restrict__ idx0,
    int* __restrict__ idx1) {
  const int lane = threadIdx.x & 63;
  const int qg = (blockIdx.x * 256 + threadIdx.x) >> 6;  // 0..16383
  const int b = qg >> 11;
  const float qx = qxyz[qg * 3 + 0];
  const float qy = qxyz[qg * 3 + 1];
  const float qz = qxyz[qg * 3 + 2];
  const float A = sumsq3(qx, qy, qz);
  const float* sx = xs + b * N_SUP;
  const float* sy = ys + b * N_SUP;
  const float* sz = zs + b * N_SUP;
  const float* sq = bsq + b * N_SUP;
  int* o0 = idx0 + qg * 16;
  int* o1 = idx1 + qg * 32;
  int cnt0 = 0, cnt1 = 0, first0 = 0, first1 = 0;
  const unsigned long long ltmask = (1ull << lane) - 1ull;
  for (int base = 0; base < N_SUP; base += 64) {
    int n = base + lane;
    float d = dot3(qx, qy, qz, sx[n], sy[n], sz[n]);
    float d2 = d2_expand(A, sq[n], d);
    bool in1 = d2 <= 0.04f;  // == f32(0.2*0.2 in double)
    bool in0 = d2 <= 0.01f;  // == f32(0.1*0.1 in double)
    unsigned long long m1 = __ballot(in1);
    unsigned long long m0 = __ballot(in0);
    if (in1) {
      int pos = cnt1 + __popcll(m1 & ltmask);
      if (pos < 32) o1[pos] = n;
    }
    if (in0) {
      int pos = cnt0 + __popcll(m0 & ltmask);
      if (pos < 16) o0[pos] = n;
    }
    if (cnt1 == 0 && m1 != 0ull) first1 = base + __ffsll(m1) - 1;
    if (cnt0 == 0 && m0 != 0ull) first0 = base + __ffsll(m0) - 1;
    cnt1 += __popcll(m1);
    cnt0 += __popcll(m0);
    if (cnt0 >= 16 && cnt1 >= 32) break;
  }
  for (int p = cnt0 + lane; p < 16; p += 64) o0[p] = first0;
  for (int p = cnt1 + lane; p < 32; p += 64) o1[p] = first1;
}

// ---------------------------------------------------------------------------
// Grouped MLP. Block = 256 threads = 4 waves, 64 rows (= Q queries x K
// neighbors), lane == row. Activations in LDS with odd strides (bank-clean),
// weights are wave-uniform -> scalar loads feeding v_fmac: VALU-bound.
// ---------------------------------------------------------------------------
template <int CIN, int SIN, int D, int SOUT>
__device__ __forceinline__ void dense_layer(const float* __restrict__ hin,
                                            float* __restrict__ hout,
                                            const float* __restrict__ W,
                                            const float* __restrict__ Bv,
                                            int w, int lane) {
  constexpr int CH = D / 16;
#pragma unroll
  for (int pass = 0; pass * 4 < CH; ++pass) {
    const int chunk = pass * 4 + w;
    if (chunk < CH) {  // wave-uniform branch
      const int co = chunk * 16;
      float acc[16];
#pragma unroll
      for (int j = 0; j < 16; ++j) acc[j] = Bv[co + j];
      const float* hr = hin + lane * SIN;
      const float* wp = W + co;
#pragma unroll 4
      for (int c = 0; c < CIN; ++c) {
        float a = hr[c];
#pragma unroll
        for (int j = 0; j < 16; ++j) acc[j] = fmaf(a, wp[c * D + j], acc[j]);
      }
      float* ho = hout + lane * SOUT + co;
#pragma unroll
      for (int j = 0; j < 16; ++j) ho[j] = fmaxf(acc[j], 0.0f);
    }
  }
}

template <int K, int Q, int C2, int S2, int CHOFF>
__global__ __launch_bounds__(256, 4) void mlp_kernel(
    const int* __restrict__ idxl, const float* __restrict__ qxyz,
    const float* __restrict__ xs, const float* __restrict__ ys,
    const float* __restrict__ zs, const float* __restrict__ fT,
    const float* __restrict__ W1, const float* __restrict__ B1,
    const float* __restrict__ W2, const float* __restrict__ B2,
    const float* __restrict__ W3, const float* __restrict__ B3,
    float* __restrict__ outf) {
  constexpr int S0 = 67, S1 = 65;
  constexpr int H0 = 64 * S0, H1 = 64 * S1, H2 = 64 * S2;
  constexpr int SM = H1 + (H2 > H0 ? H2 : H0);
  __shared__ float smem[SM];
  float* h1 = smem;       // layer1 output
  float* h0 = smem + H1;  // gathered input; dead after layer1
  float* h2 = smem + H1;  // layer2 output overlays h0
  const int t = threadIdx.x;
  const int w = __builtin_amdgcn_readfirstlane(t >> 6);
  const int lane = t & 63;
  // ---- gather h0: [rel_x, rel_y, rel_z, feat0..63] per row ----
  for (int e = t; e < H0; e += 256) {
    int r = e / S0, c = e - r * S0;
    int qi = r / K, k = r - qi * K;
    int qg = blockIdx.x * Q + qi;
    int b = qg >> 11;
    int n = idxl[qg * K + k];
    float v;
    if (c < 3) {
      const float* sp = (c == 0) ? xs : (c == 1) ? ys : zs;
      v = sp[b * N_SUP + n] - qxyz[qg * 3 + c];
    } else {
      v = fT[(b * N_SUP + n) * 64 + (c - 3)];
    }
    h0[e] = v;
  }
  __syncthreads();
  dense_layer<67, S0, 64, S1>(h0, h1, W1, B1, w, lane);
  __syncthreads();
  dense_layer<64, S1, C2, S2>(h1, h2, W2, B2, w, lane);
  __syncthreads();
  // ---- layer3 (C2 -> 128) + relu + maxpool over K + channel-major write ----
#pragma unroll
  for (int pass = 0; pass < 2; ++pass) {
    const int co = (pass * 4 + w) * 16;
    float acc[16];
#pragma unroll
    for (int j = 0; j < 16; ++j) acc[j] = B3[co + j];
    const float* hr = h2 + lane * S2;
#pragma unroll 4
    for (int c = 0; c < C2; ++c) {
      float a = hr[c];
#pragma unroll
      for (int j = 0; j < 16; ++j) acc[j] = fmaf(a, W3[c * 128 + co + j], acc[j]);
    }
#pragma unroll
    for (int j = 0; j < 16; ++j) acc[j] = fmaxf(acc[j], 0.0f);
#pragma unroll
    for (int off = K / 2; off >= 1; off >>= 1) {
#pragma unroll
      for (int j = 0; j < 16; ++j)
        acc[j] = fmaxf(acc[j], __shfl_xor(acc[j], off));
    }
    if ((lane & (K - 1)) == 0) {
      int qg = blockIdx.x * Q + (lane / K);
      int b = qg >> 11, s = qg & 2047;
      float* dst = outf + ((b * 256 + CHOFF + co) * 2048 + s);
#pragma unroll
      for (int j = 0; j < 16; ++j) dst[j * 2048] = acc[j];
    }
  }
}

// ---------------------------------------------------------------------------
// ws layout (floats): xs[65536] ys[65536] zs[65536] bsq[65536]
// featsT[8*8192*64] then idx0 (8*2048*16 int), idx1 (8*2048*32 int) ~20 MB
// ---------------------------------------------------------------------------
extern "C" void kernel_launch(void* const* d_in, const int* in_sizes, int n_in,
                              void* d_out, int out_size, void* d_ws,
                              size_t ws_size, hipStream_t stream) {
  const float* xyz = (const float*)d_in[0];
  const float* feats = (const float*)d_in[1];
  const float* wt[12];
  for (int i = 0; i < 12; ++i) wt[i] = (const float*)d_in[2 + i];

  float* ws = (float*)d_ws;
  float* xs = ws;
  float* ys = ws + 65536;
  float* zs = ws + 131072;
  float* bsq = ws + 196608;
  float* fT = ws + 262144;                 // 4194304 floats
  int* idx0 = (int*)(ws + 4456448);        // 262144 ints
  int* idx1 = idx0 + 262144;               // 524288 ints

  float* qxyz = (float*)d_out;             // (8,2048,3)
  float* outf = qxyz + 8 * 2048 * 3;       // (8,256,2048)

  prep_xyz_kernel<<<dim3(256), dim3(256), 0, stream>>>(xyz, xs, ys, zs, bsq);
  transpose_feats_kernel<<<dim3(1024), dim3(256), 0, stream>>>(feats, fT);
  fps_kernel<<<dim3(8), dim3(512), 0, stream>>>(xs, ys, zs, qxyz);
  ballquery_kernel<<<dim3(4096), dim3(256), 0, stream>>>(qxyz, xs, ys, zs, bsq,
                                                         idx0, idx1);
  mlp_kernel<16, 4, 64, 65, 0><<<dim3(4096), dim3(256), 0, stream>>>(
      idx0, qxyz, xs, ys, zs, fT, wt[0], wt[1], wt[2], wt[3], wt[4], wt[5],
      outf);
  mlp_kernel<32, 2, 96, 97, 128><<<dim3(8192), dim3(256), 0, stream>>>(
      idx1, qxyz, xs, ys, zs, fT, wt[6], wt[7], wt[8], wt[9], wt[10], wt[11],
      outf);
}

// Round 3
// 3111.526 us; speedup vs baseline: 1.7516x; 1.0103x over previous
//
#include <hip/hip_runtime.h>

#define N_SUP 8192
#define N_QPT 2048

typedef float v2f __attribute__((ext_vector_type(2)));

// ---------------------------------------------------------------------------
// Exactness helpers: the reference index selection (FPS argmax, ball-query
// membership) must match numpy's plain fp32 arithmetic bit-for-bit, so fma
// contraction is disabled for these expressions.
// ---------------------------------------------------------------------------
__device__ __forceinline__ float sumsq3(float x, float y, float z) {
#pragma clang fp contract(off)
  return x * x + y * y + z * z;  // ((x*x + y*y) + z*z)
}

__device__ __forceinline__ float dot3(float ax, float ay, float az,
                                      float bx, float by, float bz) {
#pragma clang fp contract(off)
  return ax * bx + ay * by + az * bz;
}

__device__ __forceinline__ float d2_expand(float A, float Bn, float d) {
#pragma clang fp contract(off)
  return (A + Bn) - 2.0f * d;  // matches (|q|^2 + |s|^2) - 2*dot
}

// f32 max across a wave via DPP: row_shr 1/2/4/8 then row_bcast15/31.
// Lane 63 ends with the wave max. Invalid source lanes fall back to old=m
// (identity under max).
template <int CTRL>
__device__ __forceinline__ float dppmax(float m) {
  int mi = __float_as_int(m);
  int mv = __builtin_amdgcn_update_dpp(mi, mi, CTRL, 0xf, 0xf, false);
  return fmaxf(m, __int_as_float(mv));
}

__device__ __forceinline__ float wavemax_dpp(float m) {
  m = dppmax<0x111>(m);  // row_shr:1
  m = dppmax<0x112>(m);  // row_shr:2
  m = dppmax<0x114>(m);  // row_shr:4
  m = dppmax<0x118>(m);  // row_shr:8  -> lane15/31/47/63 hold row maxes
  m = dppmax<0x142>(m);  // row_bcast15
  m = dppmax<0x143>(m);  // row_bcast31 -> lane 63 = wave max
  return m;
}

// ---------------------------------------------------------------------------
// prep: xyz (B,N,3) -> SoA xs/ys/zs + per-point squared norms
// ---------------------------------------------------------------------------
__global__ __launch_bounds__(256) void prep_xyz_kernel(
    const float* __restrict__ xyz, float* __restrict__ xs,
    float* __restrict__ ys, float* __restrict__ zs, float* __restrict__ bsq) {
  int p = blockIdx.x * 256 + threadIdx.x;  // 0..B*N-1
  float x = xyz[p * 3 + 0];
  float y = xyz[p * 3 + 1];
  float z = xyz[p * 3 + 2];
  xs[p] = x; ys[p] = y; zs[p] = z;
  bsq[p] = sumsq3(x, y, z);
}

// ---------------------------------------------------------------------------
// transpose features (B,C=64,N) -> (B,N,64) for coalesced gathers
// ---------------------------------------------------------------------------
__global__ __launch_bounds__(256) void transpose_feats_kernel(
    const float* __restrict__ feats, float* __restrict__ fT) {
  __shared__ float tile[64][65];
  int b = blockIdx.x >> 7;           // 128 n-tiles per batch
  int nb = (blockIdx.x & 127) << 6;
  int t = threadIdx.x;
#pragma unroll
  for (int i = 0; i < 16; ++i) {
    int e = i * 256 + t;
    int c = e >> 6, n = e & 63;     // consecutive lanes -> consecutive n
    tile[n][c] = feats[(b * 64 + c) * N_SUP + nb + n];
  }
  __syncthreads();
#pragma unroll
  for (int i = 0; i < 16; ++i) {
    int e = i * 256 + t;
    int n = e >> 6, c = e & 63;     // consecutive lanes -> consecutive c
    fT[(b * N_SUP + nb + n) * 64 + c] = tile[n][c];
  }
}

// ---------------------------------------------------------------------------
// FPS: one block per batch, 1024 threads, 8 points per thread in registers.
//
// Per iteration:
//   1. sweep: dm = min(dm, |p-l|^2) on float2 lanes (v_pk_* eligible), track
//      only the max VALUE (v_max3), no index bookkeeping.
//   2. DPP wave max -> 16 LDS partials -> barrier -> all threads fold 16
//      floats (float4 loads) to the global max g.
//   3. index recovery: each thread rescans its register dm[] for == g (fp max
//      is exact selection, so equality is bit-exact) and atomicMin's the
//      ORIGINAL point index into a rotating LDS slot -> numpy first-index
//      tie-break. 3-slot rotation + the 2 barriers make the reset race-free.
//   4. winner coords fetched from a 96 KB LDS mirror.
// ---------------------------------------------------------------------------
__global__ __launch_bounds__(1024, 1) void fps_kernel(
    const float* __restrict__ xs, const float* __restrict__ ys,
    const float* __restrict__ zs, float* __restrict__ qxyz) {
  const int b = blockIdx.x;
  const int t = threadIdx.x;
  __shared__ float sx[N_SUP], sy[N_SUP], sz[N_SUP];  // 96 KB coord mirror
  __shared__ __align__(16) float s_pmax[2][16];
  __shared__ int s_widx[3];
  const float* bx = xs + b * N_SUP;
  const float* by = ys + b * N_SUP;
  const float* bz = zs + b * N_SUP;
  v2f px[4], py[4], pz[4], dm[4];
#pragma unroll
  for (int j = 0; j < 4; ++j) {
    int n0 = t + (2 * j) * 1024, n1 = t + (2 * j + 1) * 1024;
    float x0 = bx[n0], x1 = bx[n1];
    float y0 = by[n0], y1 = by[n1];
    float z0 = bz[n0], z1 = bz[n1];
    px[j] = (v2f){x0, x1}; py[j] = (v2f){y0, y1}; pz[j] = (v2f){z0, z1};
    sx[n0] = x0; sx[n1] = x1;
    sy[n0] = y0; sy[n1] = y1;
    sz[n0] = z0; sz[n1] = z1;
    dm[j] = (v2f){1e10f, 1e10f};
  }
  if (t < 3) s_widx[t] = 0x7fffffff;
  float lx = bx[0], ly = by[0], lz = bz[0];
  float* q = qxyz + b * N_QPT * 3;
  if (t == 0) { q[0] = lx; q[1] = ly; q[2] = lz; }
  for (int it = 1; it < N_QPT; ++it) {
    // x + (-lx) rounds identically to x - lx; pre-negate once.
    float nx = -lx, ny = -ly, nz = -lz;
    v2f nx2 = (v2f){nx, nx}, ny2 = (v2f){ny, ny}, nz2 = (v2f){nz, nz};
    float lm = -1.0f;
#pragma unroll
    for (int j = 0; j < 4; ++j) {
#pragma clang fp contract(off)
      v2f dx = px[j] + nx2;
      v2f dy = py[j] + ny2;
      v2f dz = pz[j] + nz2;
      v2f s = dx * dx + dy * dy;
      s = s + dz * dz;
      v2f nd = __builtin_elementwise_min(dm[j], s);
      dm[j] = nd;
      lm = fmaxf(lm, fmaxf(nd.x, nd.y));  // v_max3
    }
    float wm = wavemax_dpp(lm);
    const int par = it & 1;
    if ((t & 63) == 63) s_pmax[par][t >> 6] = wm;
    if (t == 2) s_widx[(it + 1) % 3] = 0x7fffffff;  // reset future slot
    __syncthreads();
    const float4* pm = (const float4*)&s_pmax[par][0];
    float4 A = pm[0], B = pm[1], C = pm[2], D = pm[3];
    float g = fmaxf(fmaxf(fmaxf(A.x, A.y), fmaxf(A.z, A.w)),
                    fmaxf(fmaxf(B.x, B.y), fmaxf(B.z, B.w)));
    float g2 = fmaxf(fmaxf(fmaxf(C.x, C.y), fmaxf(C.z, C.w)),
                     fmaxf(fmaxf(D.x, D.y), fmaxf(D.z, D.w)));
    g = fmaxf(g, g2);
    // descending scan: final assignment = smallest original index
    int li = 0x7fffffff;
#pragma unroll
    for (int j = 3; j >= 0; --j) {
      if (dm[j].y == g) li = t + (2 * j + 1) * 1024;
      if (dm[j].x == g) li = t + (2 * j) * 1024;
    }
    if (li != 0x7fffffff) atomicMin(&s_widx[it % 3], li);
    __syncthreads();
    int ri = s_widx[it % 3];
    lx = sx[ri]; ly = sy[ri]; lz = sz[ri];
    if (t == 0) { q[it * 3 + 0] = lx; q[it * 3 + 1] = ly; q[it * 3 + 2] = lz; }
  }
}

// ---------------------------------------------------------------------------
// Ball query: one wave per query, both radii in one scan. First-K-by-index
// via ballot + prefix popcount; early exit when both lists are full; pad with
// the first in-ball index (always exists: the query point itself, d2==0).
// ---------------------------------------------------------------------------
__global__ __launch_bounds__(256) void ballquery_kernel(
    const float* __restrict__ qxyz, const float* __restrict__ xs,
    const float* __restrict__ ys, const float* __restrict__ zs,
    const float* __restrict__ bsq, int* __restrict__ idx0,
    int* __restrict__ idx1) {
  const int lane = threadIdx.x & 63;
  const int qg = (blockIdx.x * 256 + threadIdx.x) >> 6;  // 0..16383
  const int b = qg >> 11;
  const float qx = qxyz[qg * 3 + 0];
  const float qy = qxyz[qg * 3 + 1];
  const float qz = qxyz[qg * 3 + 2];
  const float A = sumsq3(qx, qy, qz);
  const float* sx = xs + b * N_SUP;
  const float* sy = ys + b * N_SUP;
  const float* sz = zs + b * N_SUP;
  const float* sq = bsq + b * N_SUP;
  int* o0 = idx0 + qg * 16;
  int* o1 = idx1 + qg * 32;
  int cnt0 = 0, cnt1 = 0, first0 = 0, first1 = 0;
  const unsigned long long ltmask = (1ull << lane) - 1ull;
  for (int base = 0; base < N_SUP; base += 64) {
    int n = base + lane;
    float d = dot3(qx, qy, qz, sx[n], sy[n], sz[n]);
    float d2 = d2_expand(A, sq[n], d);
    bool in1 = d2 <= 0.04f;  // == f32(0.2*0.2 in double)
    bool in0 = d2 <= 0.01f;  // == f32(0.1*0.1 in double)
    unsigned long long m1 = __ballot(in1);
    unsigned long long m0 = __ballot(in0);
    if (in1) {
      int pos = cnt1 + __popcll(m1 & ltmask);
      if (pos < 32) o1[pos] = n;
    }
    if (in0) {
      int pos = cnt0 + __popcll(m0 & ltmask);
      if (pos < 16) o0[pos] = n;
    }
    if (cnt1 == 0 && m1 != 0ull) first1 = base + __ffsll(m1) - 1;
    if (cnt0 == 0 && m0 != 0ull) first0 = base + __ffsll(m0) - 1;
    cnt1 += __popcll(m1);
    cnt0 += __popcll(m0);
    if (cnt0 >= 16 && cnt1 >= 32) break;
  }
  for (int p = cnt0 + lane; p < 16; p += 64) o0[p] = first0;
  for (int p = cnt1 + lane; p < 32; p += 64) o1[p] = first1;
}

// ---------------------------------------------------------------------------
// Grouped MLP. Block = 256 threads = 4 waves, 64 rows (= Q queries x K
// neighbors), lane == row. Activations in LDS with odd strides (bank-clean),
// weights are wave-uniform -> scalar loads feeding v_fmac: VALU-bound.
// ---------------------------------------------------------------------------
template <int CIN, int SIN, int D, int SOUT>
__device__ __forceinline__ void dense_layer(const float* __restrict__ hin,
                                            float* __restrict__ hout,
                                            const float* __restrict__ W,
                                            const float* __restrict__ Bv,
                                            int w, int lane) {
  constexpr int CH = D / 16;
#pragma unroll
  for (int pass = 0; pass * 4 < CH; ++pass) {
    const int chunk = pass * 4 + w;
    if (chunk < CH) {  // wave-uniform branch
      const int co = chunk * 16;
      float acc[16];
#pragma unroll
      for (int j = 0; j < 16; ++j) acc[j] = Bv[co + j];
      const float* hr = hin + lane * SIN;
      const float* wp = W + co;
#pragma unroll 4
      for (int c = 0; c < CIN; ++c) {
        float a = hr[c];
#pragma unroll
        for (int j = 0; j < 16; ++j) acc[j] = fmaf(a, wp[c * D + j], acc[j]);
      }
      float* ho = hout + lane * SOUT + co;
#pragma unroll
      for (int j = 0; j < 16; ++j) ho[j] = fmaxf(acc[j], 0.0f);
    }
  }
}

template <int K, int Q, int C2, int S2, int CHOFF>
__global__ __launch_bounds__(256, 4) void mlp_kernel(
    const int* __restrict__ idxl, const float* __restrict__ qxyz,
    const float* __restrict__ xs, const float* __restrict__ ys,
    const float* __restrict__ zs, const float* __restrict__ fT,
    const float* __restrict__ W1, const float* __restrict__ B1,
    const float* __restrict__ W2, const float* __restrict__ B2,
    const float* __restrict__ W3, const float* __restrict__ B3,
    float* __restrict__ outf) {
  constexpr int S0 = 67, S1 = 65;
  constexpr int H0 = 64 * S0, H1 = 64 * S1, H2 = 64 * S2;
  constexpr int SM = H1 + (H2 > H0 ? H2 : H0);
  __shared__ float smem[SM];
  float* h1 = smem;       // layer1 output
  float* h0 = smem + H1;  // gathered input; dead after layer1
  float* h2 = smem + H1;  // layer2 output overlays h0
  const int t = threadIdx.x;
  const int w = __builtin_amdgcn_readfirstlane(t >> 6);
  const int lane = t & 63;
  // ---- gather h0: [rel_x, rel_y, rel_z, feat0..63] per row ----
  for (int e = t; e < H0; e += 256) {
    int r = e / S0, c = e - r * S0;
    int qi = r / K, k = r - qi * K;
    int qg = blockIdx.x * Q + qi;
    int b = qg >> 11;
    int n = idxl[qg * K + k];
    float v;
    if (c < 3) {
      const float* sp = (c == 0) ? xs : (c == 1) ? ys : zs;
      v = sp[b * N_SUP + n] - qxyz[qg * 3 + c];
    } else {
      v = fT[(b * N_SUP + n) * 64 + (c - 3)];
    }
    h0[e] = v;
  }
  __syncthreads();
  dense_layer<67, S0, 64, S1>(h0, h1, W1, B1, w, lane);
  __syncthreads();
  dense_layer<64, S1, C2, S2>(h1, h2, W2, B2, w, lane);
  __syncthreads();
  // ---- layer3 (C2 -> 128) + relu + maxpool over K + channel-major write ----
#pragma unroll
  for (int pass = 0; pass < 2; ++pass) {
    const int co = (pass * 4 + w) * 16;
    float acc[16];
#pragma unroll
    for (int j = 0; j < 16; ++j) acc[j] = B3[co + j];
    const float* hr = h2 + lane * S2;
#pragma unroll 4
    for (int c = 0; c < C2; ++c) {
      float a = hr[c];
#pragma unroll
      for (int j = 0; j < 16; ++j) acc[j] = fmaf(a, W3[c * 128 + co + j], acc[j]);
    }
#pragma unroll
    for (int j = 0; j < 16; ++j) acc[j] = fmaxf(acc[j], 0.0f);
#pragma unroll
    for (int off = K / 2; off >= 1; off >>= 1) {
#pragma unroll
      for (int j = 0; j < 16; ++j)
        acc[j] = fmaxf(acc[j], __shfl_xor(acc[j], off));
    }
    if ((lane & (K - 1)) == 0) {
      int qg = blockIdx.x * Q + (lane / K);
      int b = qg >> 11, s = qg & 2047;
      float* dst = outf + ((b * 256 + CHOFF + co) * 2048 + s);
#pragma unroll
      for (int j = 0; j < 16; ++j) dst[j * 2048] = acc[j];
    }
  }
}

// ---------------------------------------------------------------------------
// ws layout (floats): xs[65536] ys[65536] zs[65536] bsq[65536]
// featsT[8*8192*64] then idx0 (8*2048*16 int), idx1 (8*2048*32 int) ~20 MB
// ---------------------------------------------------------------------------
extern "C" void kernel_launch(void* const* d_in, const int* in_sizes, int n_in,
                              void* d_out, int out_size, void* d_ws,
                              size_t ws_size, hipStream_t stream) {
  const float* xyz = (const float*)d_in[0];
  const float* feats = (const float*)d_in[1];
  const float* wt[12];
  for (int i = 0; i < 12; ++i) wt[i] = (const float*)d_in[2 + i];

  float* ws = (float*)d_ws;
  float* xs = ws;
  float* ys = ws + 65536;
  float* zs = ws + 131072;
  float* bsq = ws + 196608;
  float* fT = ws + 262144;                 // 4194304 floats
  int* idx0 = (int*)(ws + 4456448);        // 262144 ints
  int* idx1 = idx0 + 262144;               // 524288 ints

  float* qxyz = (float*)d_out;             // (8,2048,3)
  float* outf = qxyz + 8 * 2048 * 3;       // (8,256,2048)

  prep_xyz_kernel<<<dim3(256), dim3(256), 0, stream>>>(xyz, xs, ys, zs, bsq);
  transpose_feats_kernel<<<dim3(1024), dim3(256), 0, stream>>>(feats, fT);
  fps_kernel<<<dim3(8), dim3(1024), 0, stream>>>(xs, ys, zs, qxyz);
  ballquery_kernel<<<dim3(4096), dim3(256), 0, stream>>>(qxyz, xs, ys, zs, bsq,
                                                         idx0, idx1);
  mlp_kernel<16, 4, 64, 65, 0><<<dim3(4096), dim3(256), 0, stream>>>(
      idx0, qxyz, xs, ys, zs, fT, wt[0], wt[1], wt[2], wt[3], wt[4], wt[5],
      outf);
  mlp_kernel<32, 2, 96, 97, 128><<<dim3(8192), dim3(256), 0, stream>>>(
      idx1, qxyz, xs, ys, zs, fT, wt[6], wt[7], wt[8], wt[9], wt[10], wt[11],
      outf);
}

// Round 4
// 2822.657 us; speedup vs baseline: 1.9309x; 1.1023x over previous
//
#include <hip/hip_runtime.h>

#define N_SUP 8192
#define N_QPT 2048

typedef float v2f __attribute__((ext_vector_type(2)));

// ---------------------------------------------------------------------------
// Exactness helpers: the reference index selection (FPS argmax, ball-query
// membership) must match numpy's plain fp32 arithmetic bit-for-bit, so fma
// contraction is disabled for these expressions.
// ---------------------------------------------------------------------------
__device__ __forceinline__ float sumsq3(float x, float y, float z) {
#pragma clang fp contract(off)
  return x * x + y * y + z * z;  // ((x*x + y*y) + z*z)
}

__device__ __forceinline__ float dot3(float ax, float ay, float az,
                                      float bx, float by, float bz) {
#pragma clang fp contract(off)
  return ax * bx + ay * by + az * bz;
}

__device__ __forceinline__ float d2_expand(float A, float Bn, float d) {
#pragma clang fp contract(off)
  return (A + Bn) - 2.0f * d;  // matches (|q|^2 + |s|^2) - 2*dot
}

// Wave reductions via DPP (row_shr 1/2/4/8, row_bcast15/31): lane 63 ends
// with the wave result. old=src => invalid lanes keep own value (identity).
template <int CTRL>
__device__ __forceinline__ float dppmax(float m) {
  int mi = __float_as_int(m);
  int mv = __builtin_amdgcn_update_dpp(mi, mi, CTRL, 0xf, 0xf, false);
  return fmaxf(m, __int_as_float(mv));
}

__device__ __forceinline__ float wavemax_dpp(float m) {
  m = dppmax<0x111>(m);  // row_shr:1
  m = dppmax<0x112>(m);  // row_shr:2
  m = dppmax<0x114>(m);  // row_shr:4
  m = dppmax<0x118>(m);  // row_shr:8
  m = dppmax<0x142>(m);  // row_bcast15
  m = dppmax<0x143>(m);  // row_bcast31 -> lane 63 = wave max
  return m;
}

template <int CTRL>
__device__ __forceinline__ unsigned dppminu(unsigned m) {
  unsigned mv = (unsigned)__builtin_amdgcn_update_dpp((int)m, (int)m, CTRL,
                                                      0xf, 0xf, false);
  return (mv < m) ? mv : m;
}

__device__ __forceinline__ unsigned wavemin_dpp(unsigned m) {
  m = dppminu<0x111>(m);
  m = dppminu<0x112>(m);
  m = dppminu<0x114>(m);
  m = dppminu<0x118>(m);
  m = dppminu<0x142>(m);
  m = dppminu<0x143>(m);  // lane 63 = wave min
  return m;
}

// ---------------------------------------------------------------------------
// prep: xyz (B,N,3) -> SoA xs/ys/zs + per-point squared norms
// ---------------------------------------------------------------------------
__global__ __launch_bounds__(256) void prep_xyz_kernel(
    const float* __restrict__ xyz, float* __restrict__ xs,
    float* __restrict__ ys, float* __restrict__ zs, float* __restrict__ bsq) {
  int p = blockIdx.x * 256 + threadIdx.x;  // 0..B*N-1
  float x = xyz[p * 3 + 0];
  float y = xyz[p * 3 + 1];
  float z = xyz[p * 3 + 2];
  xs[p] = x; ys[p] = y; zs[p] = z;
  bsq[p] = sumsq3(x, y, z);
}

// ---------------------------------------------------------------------------
// transpose features (B,C=64,N) -> (B,N,64) for coalesced gathers
// ---------------------------------------------------------------------------
__global__ __launch_bounds__(256) void transpose_feats_kernel(
    const float* __restrict__ feats, float* __restrict__ fT) {
  __shared__ float tile[64][65];
  int b = blockIdx.x >> 7;           // 128 n-tiles per batch
  int nb = (blockIdx.x & 127) << 6;
  int t = threadIdx.x;
#pragma unroll
  for (int i = 0; i < 16; ++i) {
    int e = i * 256 + t;
    int c = e >> 6, n = e & 63;     // consecutive lanes -> consecutive n
    tile[n][c] = feats[(b * 64 + c) * N_SUP + nb + n];
  }
  __syncthreads();
#pragma unroll
  for (int i = 0; i < 16; ++i) {
    int e = i * 256 + t;
    int n = e >> 6, c = e & 63;     // consecutive lanes -> consecutive c
    fT[(b * N_SUP + nb + n) * 64 + c] = tile[n][c];
  }
}

// ---------------------------------------------------------------------------
// FPS: one block per batch, 512 threads (8 waves, 2/SIMD), 16 pts/thread as
// 8 float2 groups. ONE barrier per iteration:
//   1. sweep: dm = min(dm, |p-l|^2) on float2 (v_pk_*), track max VALUE only.
//   2. DPP wave-max -> readlane(63) broadcast -> register rescan for the
//      matching SLOT (constants 0..15, inline operands) -> DPP wave-min of
//      index -> lane63 packs u64 key (val_bits<<32 | 8191-idx) -> LDS.
//   3. barrier; every wave folds the 8 keys (u64 max == argmax with
//      first-index tie-break, exactly numpy) and fetches winner coords from
//      a 96 KB LDS mirror. Double-buffered key slots (write k vs k+2 are
//      separated by barrier k+1).
// Equality rescan is exact: fp min/max select bit patterns, never round.
// ---------------------------------------------------------------------------
__global__ __launch_bounds__(512, 1) void fps_kernel(
    const float* __restrict__ xs, const float* __restrict__ ys,
    const float* __restrict__ zs, float* __restrict__ qxyz) {
  const int b = blockIdx.x;
  const int t = threadIdx.x;
  __shared__ float sx[N_SUP], sy[N_SUP], sz[N_SUP];  // 96 KB coord mirror
  __shared__ __align__(16) unsigned long long skey[2][8];
  const float* bx = xs + b * N_SUP;
  const float* by = ys + b * N_SUP;
  const float* bz = zs + b * N_SUP;
  v2f px[8], py[8], pz[8], dm[8];
#pragma unroll
  for (int j = 0; j < 8; ++j) {
    int n0 = t + (2 * j) * 512, n1 = t + (2 * j + 1) * 512;
    float x0 = bx[n0], x1 = bx[n1];
    float y0 = by[n0], y1 = by[n1];
    float z0 = bz[n0], z1 = bz[n1];
    px[j] = (v2f){x0, x1}; py[j] = (v2f){y0, y1}; pz[j] = (v2f){z0, z1};
    sx[n0] = x0; sx[n1] = x1;
    sy[n0] = y0; sy[n1] = y1;
    sz[n0] = z0; sz[n1] = z1;
    dm[j] = (v2f){1e10f, 1e10f};
  }
  float lx = bx[0], ly = by[0], lz = bz[0];
  float* q = qxyz + b * N_QPT * 3;
  if (t == 0) { q[0] = lx; q[1] = ly; q[2] = lz; }
  const int wv = t >> 6;
  const bool is63 = (t & 63) == 63;
  for (int it = 1; it < N_QPT; ++it) {
    // x + (-lx) rounds identically to x - lx; pre-negate once.
    float nx = -lx, ny = -ly, nz = -lz;
    v2f nx2 = (v2f){nx, nx}, ny2 = (v2f){ny, ny}, nz2 = (v2f){nz, nz};
    float lm = -1.0f;
#pragma unroll
    for (int j = 0; j < 8; ++j) {
#pragma clang fp contract(off)
      v2f dx = px[j] + nx2;
      v2f dy = py[j] + ny2;
      v2f dz = pz[j] + nz2;
      v2f s = dx * dx + dy * dy;
      s = s + dz * dz;
      v2f nd = __builtin_elementwise_min(dm[j], s);
      dm[j] = nd;
      lm = fmaxf(lm, fmaxf(nd.x, nd.y));  // v_max3
    }
    float wmx = wavemax_dpp(lm);  // lane 63 holds wave max
    float wm = __int_as_float(
        __builtin_amdgcn_readlane(__float_as_int(wmx), 63));  // sgpr bcast
    // slot of smallest matching index in this lane (slot s -> idx t + s*512)
    int slot = 0x10000;  // sentinel: li stays > any valid index, min-safe
#pragma unroll
    for (int j = 7; j >= 0; --j) {
      if (dm[j].y == wm) slot = 2 * j + 1;
      if (dm[j].x == wm) slot = 2 * j;
    }
    unsigned li = (unsigned)(slot * 512 + t);
    unsigned wli = wavemin_dpp(li);  // lane 63 holds wave min index
    if (is63) {
      skey[it & 1][wv] =
          (((unsigned long long)(unsigned)__float_as_int(wmx)) << 32) |
          (unsigned)(N_SUP - 1 - (int)wli);
    }
    __syncthreads();
    const ulonglong2* pk = (const ulonglong2*)&skey[it & 1][0];
    ulonglong2 A = pk[0], B = pk[1], C = pk[2], D = pk[3];
    unsigned long long k0 = (A.y > A.x) ? A.y : A.x;
    unsigned long long k1 = (B.y > B.x) ? B.y : B.x;
    unsigned long long k2 = (C.y > C.x) ? C.y : C.x;
    unsigned long long k3 = (D.y > D.x) ? D.y : D.x;
    k0 = (k1 > k0) ? k1 : k0;
    k2 = (k3 > k2) ? k3 : k2;
    k0 = (k2 > k0) ? k2 : k0;
    int ri = N_SUP - 1 - (int)(unsigned)(k0 & 0xFFFFFFFFull);
    lx = sx[ri]; ly = sy[ri]; lz = sz[ri];
    if (t == 0) { q[it * 3 + 0] = lx; q[it * 3 + 1] = ly; q[it * 3 + 2] = lz; }
  }
}

// ---------------------------------------------------------------------------
// Ball query: one wave per query, both radii in one scan. First-K-by-index
// via ballot + prefix popcount; early exit when both lists are full; pad with
// the first in-ball index (always exists: the query point itself, d2==0).
// ---------------------------------------------------------------------------
__global__ __launch_bounds__(256) void ballquery_kernel(
    const float* __restrict__ qxyz, const float* __restrict__ xs,
    const float* __restrict__ ys, const float* __restrict__ zs,
    const float* __restrict__ bsq, int* __restrict__ idx0,
    int* __restrict__ idx1) {
  const int lane = threadIdx.x & 63;
  const int qg = (blockIdx.x * 256 + threadIdx.x) >> 6;  // 0..16383
  const int b = qg >> 11;
  const float qx = qxyz[qg * 3 + 0];
  const float qy = qxyz[qg * 3 + 1];
  const float qz = qxyz[qg * 3 + 2];
  const float A = sumsq3(qx, qy, qz);
  const float* sx = xs + b * N_SUP;
  const float* sy = ys + b * N_SUP;
  const float* sz = zs + b * N_SUP;
  const float* sq = bsq + b * N_SUP;
  int* o0 = idx0 + qg * 16;
  int* o1 = idx1 + qg * 32;
  int cnt0 = 0, cnt1 = 0, first0 = 0, first1 = 0;
  const unsigned long long ltmask = (1ull << lane) - 1ull;
  for (int base = 0; base < N_SUP; base += 64) {
    int n = base + lane;
    float d = dot3(qx, qy, qz, sx[n], sy[n], sz[n]);
    float d2 = d2_expand(A, sq[n], d);
    bool in1 = d2 <= 0.04f;  // == f32(0.2*0.2 in double)
    bool in0 = d2 <= 0.01f;  // == f32(0.1*0.1 in double)
    unsigned long long m1 = __ballot(in1);
    unsigned long long m0 = __ballot(in0);
    if (in1) {
      int pos = cnt1 + __popcll(m1 & ltmask);
      if (pos < 32) o1[pos] = n;
    }
    if (in0) {
      int pos = cnt0 + __popcll(m0 & ltmask);
      if (pos < 16) o0[pos] = n;
    }
    if (cnt1 == 0 && m1 != 0ull) first1 = base + __ffsll(m1) - 1;
    if (cnt0 == 0 && m0 != 0ull) first0 = base + __ffsll(m0) - 1;
    cnt1 += __popcll(m1);
    cnt0 += __popcll(m0);
    if (cnt0 >= 16 && cnt1 >= 32) break;
  }
  for (int p = cnt0 + lane; p < 16; p += 64) o0[p] = first0;
  for (int p = cnt1 + lane; p < 32; p += 64) o1[p] = first1;
}

// ---------------------------------------------------------------------------
// Grouped MLP. Block = 256 threads = 4 waves, 64 rows (= Q queries x K
// neighbors), lane == row. Activations in LDS with odd strides (bank-clean),
// weights are wave-uniform -> scalar loads feeding v_fmac: VALU-bound.
// ---------------------------------------------------------------------------
template <int CIN, int SIN, int D, int SOUT>
__device__ __forceinline__ void dense_layer(const float* __restrict__ hin,
                                            float* __restrict__ hout,
                                            const float* __restrict__ W,
                                            const float* __restrict__ Bv,
                                            int w, int lane) {
  constexpr int CH = D / 16;
#pragma unroll
  for (int pass = 0; pass * 4 < CH; ++pass) {
    const int chunk = pass * 4 + w;
    if (chunk < CH) {  // wave-uniform branch
      const int co = chunk * 16;
      float acc[16];
#pragma unroll
      for (int j = 0; j < 16; ++j) acc[j] = Bv[co + j];
      const float* hr = hin + lane * SIN;
      const float* wp = W + co;
#pragma unroll 4
      for (int c = 0; c < CIN; ++c) {
        float a = hr[c];
#pragma unroll
        for (int j = 0; j < 16; ++j) acc[j] = fmaf(a, wp[c * D + j], acc[j]);
      }
      float* ho = hout + lane * SOUT + co;
#pragma unroll
      for (int j = 0; j < 16; ++j) ho[j] = fmaxf(acc[j], 0.0f);
    }
  }
}

template <int K, int Q, int C2, int S2, int CHOFF>
__global__ __launch_bounds__(256, 4) void mlp_kernel(
    const int* __restrict__ idxl, const float* __restrict__ qxyz,
    const float* __restrict__ xs, const float* __restrict__ ys,
    const float* __restrict__ zs, const float* __restrict__ fT,
    const float* __restrict__ W1, const float* __restrict__ B1,
    const float* __restrict__ W2, const float* __restrict__ B2,
    const float* __restrict__ W3, const float* __restrict__ B3,
    float* __restrict__ outf) {
  constexpr int S0 = 67, S1 = 65;
  constexpr int H0 = 64 * S0, H1 = 64 * S1, H2 = 64 * S2;
  constexpr int SM = H1 + (H2 > H0 ? H2 : H0);
  __shared__ float smem[SM];
  float* h1 = smem;       // layer1 output
  float* h0 = smem + H1;  // gathered input; dead after layer1
  float* h2 = smem + H1;  // layer2 output overlays h0
  const int t = threadIdx.x;
  const int w = __builtin_amdgcn_readfirstlane(t >> 6);
  const int lane = t & 63;
  // ---- gather h0: [rel_x, rel_y, rel_z, feat0..63] per row ----
  for (int e = t; e < H0; e += 256) {
    int r = e / S0, c = e - r * S0;
    int qi = r / K, k = r - qi * K;
    int qg = blockIdx.x * Q + qi;
    int b = qg >> 11;
    int n = idxl[qg * K + k];
    float v;
    if (c < 3) {
      const float* sp = (c == 0) ? xs : (c == 1) ? ys : zs;
      v = sp[b * N_SUP + n] - qxyz[qg * 3 + c];
    } else {
      v = fT[(b * N_SUP + n) * 64 + (c - 3)];
    }
    h0[e] = v;
  }
  __syncthreads();
  dense_layer<67, S0, 64, S1>(h0, h1, W1, B1, w, lane);
  __syncthreads();
  dense_layer<64, S1, C2, S2>(h1, h2, W2, B2, w, lane);
  __syncthreads();
  // ---- layer3 (C2 -> 128) + relu + maxpool over K + channel-major write ----
#pragma unroll
  for (int pass = 0; pass < 2; ++pass) {
    const int co = (pass * 4 + w) * 16;
    float acc[16];
#pragma unroll
    for (int j = 0; j < 16; ++j) acc[j] = B3[co + j];
    const float* hr = h2 + lane * S2;
#pragma unroll 4
    for (int c = 0; c < C2; ++c) {
      float a = hr[c];
#pragma unroll
      for (int j = 0; j < 16; ++j) acc[j] = fmaf(a, W3[c * 128 + co + j], acc[j]);
    }
#pragma unroll
    for (int j = 0; j < 16; ++j) acc[j] = fmaxf(acc[j], 0.0f);
#pragma unroll
    for (int off = K / 2; off >= 1; off >>= 1) {
#pragma unroll
      for (int j = 0; j < 16; ++j)
        acc[j] = fmaxf(acc[j], __shfl_xor(acc[j], off));
    }
    if ((lane & (K - 1)) == 0) {
      int qg = blockIdx.x * Q + (lane / K);
      int b = qg >> 11, s = qg & 2047;
      float* dst = outf + ((b * 256 + CHOFF + co) * 2048 + s);
#pragma unroll
      for (int j = 0; j < 16; ++j) dst[j * 2048] = acc[j];
    }
  }
}

// ---------------------------------------------------------------------------
// ws layout (floats): xs[65536] ys[65536] zs[65536] bsq[65536]
// featsT[8*8192*64] then idx0 (8*2048*16 int), idx1 (8*2048*32 int) ~20 MB
// ---------------------------------------------------------------------------
extern "C" void kernel_launch(void* const* d_in, const int* in_sizes, int n_in,
                              void* d_out, int out_size, void* d_ws,
                              size_t ws_size, hipStream_t stream) {
  const float* xyz = (const float*)d_in[0];
  const float* feats = (const float*)d_in[1];
  const float* wt[12];
  for (int i = 0; i < 12; ++i) wt[i] = (const float*)d_in[2 + i];

  float* ws = (float*)d_ws;
  float* xs = ws;
  float* ys = ws + 65536;
  float* zs = ws + 131072;
  float* bsq = ws + 196608;
  float* fT = ws + 262144;                 // 4194304 floats
  int* idx0 = (int*)(ws + 4456448);        // 262144 ints
  int* idx1 = idx0 + 262144;               // 524288 ints

  float* qxyz = (float*)d_out;             // (8,2048,3)
  float* outf = qxyz + 8 * 2048 * 3;       // (8,256,2048)

  prep_xyz_kernel<<<dim3(256), dim3(256), 0, stream>>>(xyz, xs, ys, zs, bsq);
  transpose_feats_kernel<<<dim3(1024), dim3(256), 0, stream>>>(feats, fT);
  fps_kernel<<<dim3(8), dim3(512), 0, stream>>>(xs, ys, zs, qxyz);
  ballquery_kernel<<<dim3(4096), dim3(256), 0, stream>>>(qxyz, xs, ys, zs, bsq,
                                                         idx0, idx1);
  mlp_kernel<16, 4, 64, 65, 0><<<dim3(4096), dim3(256), 0, stream>>>(
      idx0, qxyz, xs, ys, zs, fT, wt[0], wt[1], wt[2], wt[3], wt[4], wt[5],
      outf);
  mlp_kernel<32, 2, 96, 97, 128><<<dim3(8192), dim3(256), 0, stream>>>(
      idx1, qxyz, xs, ys, zs, fT, wt[6], wt[7], wt[8], wt[9], wt[10], wt[11],
      outf);
}